// Round 10
// baseline (809.416 us; speedup 1.0000x reference)
//
#include <hip/hip_runtime.h>
#include <hip/hip_bf16.h>
#include <cstdint>
#include <cstddef>

#define NN 100000
#define EE 1600000
#define GG 2048
#define EN (EE + NN)

constexpr int NB_SCAN = (NN + 255) / 256; // 391 blocks over nodes

__device__ __forceinline__ float lrelu(float v) { return v > 0.f ? v : 0.2f * v; }

// ---------------- CSR build (dst -> list of src), reused by all 3 layers ----
__global__ void k_count(const int* __restrict__ ei, int* __restrict__ deg,
                        int* __restrict__ rank) {
    int i = blockIdx.x * blockDim.x + threadIdx.x;
    if (i >= EN) return;
    int d = (i < EE) ? ei[EE + i] : (i - EE);
    rank[i] = atomicAdd(&deg[d], 1);
}

__global__ void k_scan1(const int* __restrict__ deg, int* __restrict__ offs,
                        int* __restrict__ bsums) {
    __shared__ int tmp[256];
    int tid = threadIdx.x;
    int i = blockIdx.x * 256 + tid;
    int v = (i < NN) ? deg[i] : 0;
    tmp[tid] = v; __syncthreads();
    for (int off = 1; off < 256; off <<= 1) {
        int t = (tid >= off) ? tmp[tid - off] : 0;
        __syncthreads();
        tmp[tid] += t;
        __syncthreads();
    }
    if (i < NN) offs[i] = tmp[tid] - v;   // exclusive within block
    if (tid == 255) bsums[blockIdx.x] = tmp[255];
}

__global__ void k_scan2(int* __restrict__ bsums) {
    __shared__ int tmp[512];
    int tid = threadIdx.x;
    int v = (tid < NB_SCAN) ? bsums[tid] : 0;
    tmp[tid] = v; __syncthreads();
    for (int off = 1; off < 512; off <<= 1) {
        int t = (tid >= off) ? tmp[tid - off] : 0;
        __syncthreads();
        tmp[tid] += t;
        __syncthreads();
    }
    if (tid < NB_SCAN) bsums[tid] = tmp[tid] - v;  // exclusive block offsets
}

__global__ void k_scan3(int* __restrict__ offs, const int* __restrict__ bsums) {
    int i = blockIdx.x * 256 + threadIdx.x;
    if (i < NN) offs[i] += bsums[blockIdx.x];
}

__global__ void k_scatter(const int* __restrict__ ei, const int* __restrict__ offs,
                          const int* __restrict__ rank, int* __restrict__ col) {
    int i = blockIdx.x * blockDim.x + threadIdx.x;
    if (i >= EN) return;
    int s, d;
    if (i < EE) { s = ei[i]; d = ei[EE + i]; } else { s = d = i - EE; }
    col[offs[d] + rank[i]] = s;
}

// ---------------- GEMM + fused attention-logit epilogue ---------------------
// One wave = 4 rows; x-row pointers wave-uniform (SGPR/SMEM path).
// Output written CHANNEL-SLICED: Hs[plane][node][8], plane = j>>3.
template <int FIN>
__global__ __launch_bounds__(256) void k_gemm(const float* __restrict__ X,
                                              const float* __restrict__ W,
                                              const float* __restrict__ asrc,
                                              const float* __restrict__ adst,
                                              float* __restrict__ Hs,
                                              float* __restrict__ als,
                                              float* __restrict__ ald) {
    int j  = threadIdx.x & 63;   // output col
    int ty = threadIdx.x >> 6;   // wave id 0..3
    int row = __builtin_amdgcn_readfirstlane(blockIdx.x * 16 + ty * 4);
    const float* x0 = X + (size_t)row * FIN;
    const float* x1 = x0 + FIN;
    const float* x2 = x1 + FIN;
    const float* x3 = x2 + FIN;
    float a0 = 0.f, a1 = 0.f, a2 = 0.f, a3 = 0.f;
#pragma unroll
    for (int k = 0; k < FIN; k += 4) {
        float4 xa = *(const float4*)(x0 + k);
        float4 xb = *(const float4*)(x1 + k);
        float4 xc = *(const float4*)(x2 + k);
        float4 xd = *(const float4*)(x3 + k);
        float w0 = W[(k + 0) * 64 + j];
        float w1 = W[(k + 1) * 64 + j];
        float w2 = W[(k + 2) * 64 + j];
        float w3 = W[(k + 3) * 64 + j];
        a0 += xa.x * w0 + xa.y * w1 + xa.z * w2 + xa.w * w3;
        a1 += xb.x * w0 + xb.y * w1 + xb.z * w2 + xb.w * w3;
        a2 += xc.x * w0 + xc.y * w1 + xc.z * w2 + xc.w * w3;
        a3 += xd.x * w0 + xd.y * w1 + xd.z * w2 + xd.w * w3;
    }
    int plane = j >> 3, cc = j & 7;
    float* pb = Hs + ((size_t)plane * NN + row) * 8 + cc;
    pb[0 * 8] = a0; pb[1 * 8] = a1; pb[2 * 8] = a2; pb[3 * 8] = a3;
    float asj = asrc[j], adj = adst[j];
    float accs[4] = {a0, a1, a2, a3};
#pragma unroll
    for (int r = 0; r < 4; r++) {
        float vs = accs[r] * asj;
        float vd = accs[r] * adj;
#pragma unroll
        for (int off = 8; off > 0; off >>= 1) {
            vs += __shfl_xor(vs, off, 64);
            vd += __shfl_xor(vd, off, 64);
        }
        if ((j & 15) == 0) {
            int h = j >> 4;
            als[(size_t)(row + r) * 4 + h] = vs;
            ald[(size_t)(row + r) * 4 + h] = vd;
        }
    }
}

// ---------------- normalized edge softmax -> alpha planes -------------------
// 16 lanes per node; writes alpha[h][edge] = exp(e-m)/sum for all 4 heads.
__global__ __launch_bounds__(256) void k_alpha(
    const float* __restrict__ als, const float* __restrict__ ald,
    const int* __restrict__ offs, const int* __restrict__ deg,
    const int* __restrict__ col, float* __restrict__ alpha) {
    int tid = threadIdx.x;
    int g = tid >> 4, l = tid & 15;
    int n = blockIdx.x * 16 + g;   // NN % 16 == 0
    int start = offs[n];
    int len = deg[n];
    float4 ad4 = ((const float4*)ald)[n];

    if (len <= 64) {
        float ev[4][4];
        bool  vld[4];
        float m0 = -1e30f, m1 = -1e30f, m2 = -1e30f, m3 = -1e30f;
#pragma unroll
        for (int it = 0; it < 4; it++) {
            int e = l + it * 16;
            vld[it] = (e < len);
            int s = vld[it] ? col[start + e] : 0;
            float4 a = ((const float4*)als)[s];
            ev[it][0] = lrelu(a.x + ad4.x); ev[it][1] = lrelu(a.y + ad4.y);
            ev[it][2] = lrelu(a.z + ad4.z); ev[it][3] = lrelu(a.w + ad4.w);
            if (vld[it]) {
                m0 = fmaxf(m0, ev[it][0]); m1 = fmaxf(m1, ev[it][1]);
                m2 = fmaxf(m2, ev[it][2]); m3 = fmaxf(m3, ev[it][3]);
            }
        }
#pragma unroll
        for (int off = 8; off > 0; off >>= 1) {
            m0 = fmaxf(m0, __shfl_xor(m0, off, 16));
            m1 = fmaxf(m1, __shfl_xor(m1, off, 16));
            m2 = fmaxf(m2, __shfl_xor(m2, off, 16));
            m3 = fmaxf(m3, __shfl_xor(m3, off, 16));
        }
        float w[4][4];
        float s0 = 0.f, s1 = 0.f, s2 = 0.f, s3 = 0.f;
#pragma unroll
        for (int it = 0; it < 4; it++) {
            w[it][0] = vld[it] ? __expf(ev[it][0] - m0) : 0.f;
            w[it][1] = vld[it] ? __expf(ev[it][1] - m1) : 0.f;
            w[it][2] = vld[it] ? __expf(ev[it][2] - m2) : 0.f;
            w[it][3] = vld[it] ? __expf(ev[it][3] - m3) : 0.f;
            s0 += w[it][0]; s1 += w[it][1]; s2 += w[it][2]; s3 += w[it][3];
        }
#pragma unroll
        for (int off = 8; off > 0; off >>= 1) {
            s0 += __shfl_xor(s0, off, 16); s1 += __shfl_xor(s1, off, 16);
            s2 += __shfl_xor(s2, off, 16); s3 += __shfl_xor(s3, off, 16);
        }
        float i0 = 1.f / (s0 + 1e-16f), i1 = 1.f / (s1 + 1e-16f);
        float i2 = 1.f / (s2 + 1e-16f), i3 = 1.f / (s3 + 1e-16f);
#pragma unroll
        for (int it = 0; it < 4; it++) {
            int e = l + it * 16;
            if (vld[it]) {
                alpha[0 * (size_t)EN + start + e] = w[it][0] * i0;
                alpha[1 * (size_t)EN + start + e] = w[it][1] * i1;
                alpha[2 * (size_t)EN + start + e] = w[it][2] * i2;
                alpha[3 * (size_t)EN + start + e] = w[it][3] * i3;
            }
        }
    } else {
        // rare fallback: strided recompute passes
        float m0 = -1e30f, m1 = -1e30f, m2 = -1e30f, m3 = -1e30f;
        for (int e = l; e < len; e += 16) {
            int s = col[start + e];
            float4 a = ((const float4*)als)[s];
            m0 = fmaxf(m0, lrelu(a.x + ad4.x)); m1 = fmaxf(m1, lrelu(a.y + ad4.y));
            m2 = fmaxf(m2, lrelu(a.z + ad4.z)); m3 = fmaxf(m3, lrelu(a.w + ad4.w));
        }
#pragma unroll
        for (int off = 8; off > 0; off >>= 1) {
            m0 = fmaxf(m0, __shfl_xor(m0, off, 16));
            m1 = fmaxf(m1, __shfl_xor(m1, off, 16));
            m2 = fmaxf(m2, __shfl_xor(m2, off, 16));
            m3 = fmaxf(m3, __shfl_xor(m3, off, 16));
        }
        float s0 = 0.f, s1 = 0.f, s2 = 0.f, s3 = 0.f;
        for (int e = l; e < len; e += 16) {
            int s = col[start + e];
            float4 a = ((const float4*)als)[s];
            s0 += __expf(lrelu(a.x + ad4.x) - m0); s1 += __expf(lrelu(a.y + ad4.y) - m1);
            s2 += __expf(lrelu(a.z + ad4.z) - m2); s3 += __expf(lrelu(a.w + ad4.w) - m3);
        }
#pragma unroll
        for (int off = 8; off > 0; off >>= 1) {
            s0 += __shfl_xor(s0, off, 16); s1 += __shfl_xor(s1, off, 16);
            s2 += __shfl_xor(s2, off, 16); s3 += __shfl_xor(s3, off, 16);
        }
        float i0 = 1.f / (s0 + 1e-16f), i1 = 1.f / (s1 + 1e-16f);
        float i2 = 1.f / (s2 + 1e-16f), i3 = 1.f / (s3 + 1e-16f);
        for (int e = l; e < len; e += 16) {
            int s = col[start + e];
            float4 a = ((const float4*)als)[s];
            alpha[0 * (size_t)EN + start + e] = __expf(lrelu(a.x + ad4.x) - m0) * i0;
            alpha[1 * (size_t)EN + start + e] = __expf(lrelu(a.y + ad4.y) - m1) * i1;
            alpha[2 * (size_t)EN + start + e] = __expf(lrelu(a.z + ad4.z) - m2) * i2;
            alpha[3 * (size_t)EN + start + e] = __expf(lrelu(a.w + ad4.w) - m3) * i3;
        }
    }
}

// ---------------- sliced gather: slice = blockIdx % 8 -> XCD-resident plane --
// Block = 256 threads = 128 nodes x 2 float4-chunks of an 8-channel slice.
// Per-XCD working set = one 3.2 MB Hs plane (< 4 MB L2).
__global__ __launch_bounds__(256) void k_slice(
    const float* __restrict__ Hs, const float* __restrict__ alpha,
    const int* __restrict__ offs, const int* __restrict__ deg,
    const int* __restrict__ col, const float* __restrict__ bias,
    float* __restrict__ Hout) {
    int s = blockIdx.x & 7;        // slice -> XCD (round-robin heuristic)
    int t = blockIdx.x >> 3;       // node tile
    int n = t * 128 + (threadIdx.x >> 1);
    if (n >= NN) return;
    int c  = threadIdx.x & 1;      // chunk within slice
    int c4 = s * 2 + c;            // global float4 index 0..15
    int h  = c4 >> 2;              // head
    const float*  ap = alpha + (size_t)h * EN;
    const float4* Hp = (const float4*)Hs + (size_t)s * NN * 2 + c;
    int start = offs[n];
    int len = deg[n];
    const int*   cp  = col + start;
    const float* app = ap + start;
    float4 acc = {0.f, 0.f, 0.f, 0.f};
    int e = 0;
    for (; e + 4 <= len; e += 4) {   // 4 rows in flight per lane
        int i0 = cp[e], i1 = cp[e + 1], i2 = cp[e + 2], i3 = cp[e + 3];
        float a0 = app[e], a1 = app[e + 1], a2 = app[e + 2], a3 = app[e + 3];
        float4 h0 = Hp[(size_t)i0 * 2];
        float4 h1 = Hp[(size_t)i1 * 2];
        float4 h2 = Hp[(size_t)i2 * 2];
        float4 h3 = Hp[(size_t)i3 * 2];
        acc.x += a0 * h0.x + a1 * h1.x + a2 * h2.x + a3 * h3.x;
        acc.y += a0 * h0.y + a1 * h1.y + a2 * h2.y + a3 * h3.y;
        acc.z += a0 * h0.z + a1 * h1.z + a2 * h2.z + a3 * h3.z;
        acc.w += a0 * h0.w + a1 * h1.w + a2 * h2.w + a3 * h3.w;
    }
    for (; e < len; e++) {
        int i0 = cp[e];
        float a0 = app[e];
        float4 h0 = Hp[(size_t)i0 * 2];
        acc.x += a0 * h0.x; acc.y += a0 * h0.y;
        acc.z += a0 * h0.z; acc.w += a0 * h0.w;
    }
    float4 b4 = ((const float4*)bias)[c4];
    float4 o4;
    o4.x = fmaxf(acc.x + b4.x, 0.f);
    o4.y = fmaxf(acc.y + b4.y, 0.f);
    o4.z = fmaxf(acc.z + b4.z, 0.f);
    o4.w = fmaxf(acc.w + b4.w, 0.f);
    ((float4*)Hout)[(size_t)n * 16 + c4] = o4;   // row-major for next GEMM
}

// ---------------- pooling + head ---------------------------------------------
__global__ void k_out_init(const float* __restrict__ head_b, float* __restrict__ out) {
    int g = blockIdx.x * blockDim.x + threadIdx.x;
    if (g < GG) out[g] = head_b[0];
}

__global__ void k_pool(const float* __restrict__ H, const int* __restrict__ batch,
                       const float* __restrict__ hw, float* __restrict__ out) {
    int n = blockIdx.x * blockDim.x + threadIdx.x;
    if (n >= NN) return;
    const float4* hp = (const float4*)(H + (size_t)n * 64);
    const float4* wp = (const float4*)hw;
    float t = 0.f;
#pragma unroll
    for (int k = 0; k < 16; k++) {
        float4 a = hp[k]; float4 b = wp[k];
        t += a.x * b.x + a.y * b.y + a.z * b.z + a.w * b.w;
    }
    atomicAdd(&out[batch[n]], t);
}

// ---------------- launch -----------------------------------------------------
extern "C" void kernel_launch(void* const* d_in, const int* in_sizes, int n_in,
                              void* d_out, int out_size, void* d_ws, size_t ws_size,
                              hipStream_t stream) {
    const float* x     = (const float*)d_in[0];
    const int*   ei    = (const int*)d_in[1];
    const int*   batch = (const int*)d_in[2];
    const float* Wm[3] = {(const float*)d_in[3], (const float*)d_in[7],  (const float*)d_in[11]};
    const float* As[3] = {(const float*)d_in[4], (const float*)d_in[8],  (const float*)d_in[12]};
    const float* Ad[3] = {(const float*)d_in[5], (const float*)d_in[9],  (const float*)d_in[13]};
    const float* Bb[3] = {(const float*)d_in[6], (const float*)d_in[10], (const float*)d_in[14]};
    const float* hw = (const float*)d_in[15];
    const float* hb = (const float*)d_in[16];
    float* out = (float*)d_out;

    uint8_t* w = (uint8_t*)d_ws;
    auto alloc = [&](size_t bytes) -> void* {
        void* p = (void*)w;
        w += (bytes + 255) & ~(size_t)255;
        return p;
    };
    float* Hs    = (float*)alloc((size_t)8 * NN * 8 * 4);    // sliced gather planes
    float* Bf    = (float*)alloc((size_t)NN * 64 * 4);       // aggregated output
    float* als   = (float*)alloc((size_t)NN * 4 * 4);
    float* ald   = (float*)alloc((size_t)NN * 4 * 4);
    int*   deg   = (int*)alloc((size_t)NN * 4);
    int*   offs  = (int*)alloc((size_t)NN * 4);
    int*   col   = (int*)alloc((size_t)EN * 4);
    float* alpha = (float*)alloc((size_t)4 * EN * 4);        // 4 head planes
    int*   bsums = (int*)alloc((size_t)((NB_SCAN + 63) & ~63) * 4);
    int*   rank  = (int*)alpha;  // alias: rank dead before first k_alpha write

    hipMemsetAsync(deg, 0, (size_t)NN * 4, stream);

    int eb = (EN + 255) / 256;
    k_count  <<<eb, 256, 0, stream>>>(ei, deg, rank);
    k_scan1  <<<NB_SCAN, 256, 0, stream>>>(deg, offs, bsums);
    k_scan2  <<<1, 512, 0, stream>>>(bsums);
    k_scan3  <<<NB_SCAN, 256, 0, stream>>>(offs, bsums);
    k_scatter<<<eb, 256, 0, stream>>>(ei, offs, rank, col);
    k_out_init<<<(GG + 255) / 256, 256, 0, stream>>>(hb, out);

    int slice_blocks = ((NN + 127) / 128) * 8;   // 782 * 8
    const float* cur_in = x;
    for (int L = 0; L < 3; L++) {
        if (L == 0)
            k_gemm<128><<<NN / 16, 256, 0, stream>>>(
                cur_in, Wm[L], As[L], Ad[L], Hs, als, ald);
        else
            k_gemm<64><<<NN / 16, 256, 0, stream>>>(
                cur_in, Wm[L], As[L], Ad[L], Hs, als, ald);
        k_alpha<<<NN / 16, 256, 0, stream>>>(als, ald, offs, deg, col, alpha);
        k_slice<<<slice_blocks, 256, 0, stream>>>(Hs, alpha, offs, deg, col, Bb[L], Bf);
        cur_in = Bf;
    }
    k_pool<<<(NN + 255) / 256, 256, 0, stream>>>(Bf, batch, hw, out);
}

// Round 11
// 542.936 us; speedup vs baseline: 1.4908x; 1.4908x over previous
//
#include <hip/hip_runtime.h>
#include <hip/hip_bf16.h>
#include <cstdint>
#include <cstddef>

#define NN 100000
#define EE 1600000
#define GG 2048
#define EN (EE + NN)

constexpr int NB_SCAN = (NN + 255) / 256; // 391 blocks over nodes

__device__ __forceinline__ float lrelu(float v) { return v > 0.f ? v : 0.2f * v; }

// ---------------- CSR build (dst -> list of src), reused by all 3 layers ----
__global__ void k_count(const int* __restrict__ ei, int* __restrict__ deg,
                        int* __restrict__ rank) {
    int i = blockIdx.x * blockDim.x + threadIdx.x;
    if (i >= EN) return;
    int d = (i < EE) ? ei[EE + i] : (i - EE);
    rank[i] = atomicAdd(&deg[d], 1);
}

__global__ void k_scan1(const int* __restrict__ deg, int* __restrict__ offs,
                        int* __restrict__ bsums) {
    __shared__ int tmp[256];
    int tid = threadIdx.x;
    int i = blockIdx.x * 256 + tid;
    int v = (i < NN) ? deg[i] : 0;
    tmp[tid] = v; __syncthreads();
    for (int off = 1; off < 256; off <<= 1) {
        int t = (tid >= off) ? tmp[tid - off] : 0;
        __syncthreads();
        tmp[tid] += t;
        __syncthreads();
    }
    if (i < NN) offs[i] = tmp[tid] - v;   // exclusive within block
    if (tid == 255) bsums[blockIdx.x] = tmp[255];
}

__global__ void k_scan2(int* __restrict__ bsums) {
    __shared__ int tmp[512];
    int tid = threadIdx.x;
    int v = (tid < NB_SCAN) ? bsums[tid] : 0;
    tmp[tid] = v; __syncthreads();
    for (int off = 1; off < 512; off <<= 1) {
        int t = (tid >= off) ? tmp[tid - off] : 0;
        __syncthreads();
        tmp[tid] += t;
        __syncthreads();
    }
    if (tid < NB_SCAN) bsums[tid] = tmp[tid] - v;  // exclusive block offsets
}

__global__ void k_scan3(int* __restrict__ offs, const int* __restrict__ bsums) {
    int i = blockIdx.x * 256 + threadIdx.x;
    if (i < NN) offs[i] += bsums[blockIdx.x];
}

__global__ void k_scatter(const int* __restrict__ ei, const int* __restrict__ offs,
                          const int* __restrict__ rank, int* __restrict__ col) {
    int i = blockIdx.x * blockDim.x + threadIdx.x;
    if (i >= EN) return;
    int s, d;
    if (i < EE) { s = ei[i]; d = ei[EE + i]; } else { s = d = i - EE; }
    col[offs[d] + rank[i]] = s;
}

// ---------------- GEMM + fused attention-logit epilogue ---------------------
// One wave = 4 rows; x-row pointers wave-uniform (SGPR/SMEM path); row-major H.
template <int FIN>
__global__ __launch_bounds__(256) void k_gemm(const float* __restrict__ X,
                                              const float* __restrict__ W,
                                              const float* __restrict__ asrc,
                                              const float* __restrict__ adst,
                                              float* __restrict__ H,
                                              float* __restrict__ als,
                                              float* __restrict__ ald) {
    int j  = threadIdx.x & 63;   // output col
    int ty = threadIdx.x >> 6;   // wave id 0..3
    int row = __builtin_amdgcn_readfirstlane(blockIdx.x * 16 + ty * 4);
    const float* x0 = X + (size_t)row * FIN;
    const float* x1 = x0 + FIN;
    const float* x2 = x1 + FIN;
    const float* x3 = x2 + FIN;
    float a0 = 0.f, a1 = 0.f, a2 = 0.f, a3 = 0.f;
#pragma unroll
    for (int k = 0; k < FIN; k += 4) {
        float4 xa = *(const float4*)(x0 + k);
        float4 xb = *(const float4*)(x1 + k);
        float4 xc = *(const float4*)(x2 + k);
        float4 xd = *(const float4*)(x3 + k);
        float w0 = W[(k + 0) * 64 + j];
        float w1 = W[(k + 1) * 64 + j];
        float w2 = W[(k + 2) * 64 + j];
        float w3 = W[(k + 3) * 64 + j];
        a0 += xa.x * w0 + xa.y * w1 + xa.z * w2 + xa.w * w3;
        a1 += xb.x * w0 + xb.y * w1 + xb.z * w2 + xb.w * w3;
        a2 += xc.x * w0 + xc.y * w1 + xc.z * w2 + xc.w * w3;
        a3 += xd.x * w0 + xd.y * w1 + xd.z * w2 + xd.w * w3;
    }
    H[(size_t)(row + 0) * 64 + j] = a0;
    H[(size_t)(row + 1) * 64 + j] = a1;
    H[(size_t)(row + 2) * 64 + j] = a2;
    H[(size_t)(row + 3) * 64 + j] = a3;
    float asj = asrc[j], adj = adst[j];
    float accs[4] = {a0, a1, a2, a3};
#pragma unroll
    for (int r = 0; r < 4; r++) {
        float vs = accs[r] * asj;
        float vd = accs[r] * adj;
#pragma unroll
        for (int off = 8; off > 0; off >>= 1) {
            vs += __shfl_xor(vs, off, 64);
            vd += __shfl_xor(vd, off, 64);
        }
        if ((j & 15) == 0) {
            int h = j >> 4;
            als[(size_t)(row + r) * 4 + h] = vs;
            ald[(size_t)(row + r) * 4 + h] = vd;
        }
    }
}

// 16 lanes per node: fused softmax + fp32 row gather.
// LDS holds ONLY edge weights (16.6 KB -> 8 blocks/CU, full wave occupancy);
// gather re-reads col from global (sequential stream) and runs 8 rows deep.
#define LWPITCH 260   // 64*4 + 4 pad words
__global__ __launch_bounds__(256) void k_agg(
    const float* __restrict__ H, const float* __restrict__ als,
    const float* __restrict__ ald, const int* __restrict__ offs,
    const int* __restrict__ deg, const int* __restrict__ col,
    const float* __restrict__ bias, float* __restrict__ Hout,
    const int* __restrict__ batch, const float* __restrict__ hw,
    float* __restrict__ out, int last) {
    __shared__ float lws[16 * LWPITCH];  // [group][edge*4 + head]
    int tid = threadIdx.x;
    int g = tid >> 4;          // group (node) 0..15
    int l = tid & 15;          // lane in group = float4-chunk index 0..15
    int n = blockIdx.x * 16 + g;   // NN % 16 == 0
    int start = offs[n];
    int len = deg[n];
    float4 ad4 = ((const float4*)ald)[n];
    int hsel = l >> 2;         // head of this lane's channel quad
    const float4* Hp = (const float4*)H + l;
    const int* cp = col + start;
    float* lw = lws + g * LWPITCH;
    bool fast = (len <= 64);
    float inv = 1.f;

    if (fast) {
        // ---- stage: lane e (of 16) owns edges e, e+16, e+32, e+48 ----
        float ev[4][4];
        bool  vld[4];
        float m0 = -1e30f, m1 = -1e30f, m2 = -1e30f, m3 = -1e30f;
#pragma unroll
        for (int it = 0; it < 4; it++) {
            int e = l + it * 16;
            vld[it] = (e < len);
            int s = vld[it] ? cp[e] : 0;
            float4 a = ((const float4*)als)[s];
            ev[it][0] = lrelu(a.x + ad4.x); ev[it][1] = lrelu(a.y + ad4.y);
            ev[it][2] = lrelu(a.z + ad4.z); ev[it][3] = lrelu(a.w + ad4.w);
            if (vld[it]) {
                m0 = fmaxf(m0, ev[it][0]); m1 = fmaxf(m1, ev[it][1]);
                m2 = fmaxf(m2, ev[it][2]); m3 = fmaxf(m3, ev[it][3]);
            }
        }
#pragma unroll
        for (int off = 8; off > 0; off >>= 1) {
            m0 = fmaxf(m0, __shfl_xor(m0, off, 16));
            m1 = fmaxf(m1, __shfl_xor(m1, off, 16));
            m2 = fmaxf(m2, __shfl_xor(m2, off, 16));
            m3 = fmaxf(m3, __shfl_xor(m3, off, 16));
        }
        float s0 = 0.f, s1 = 0.f, s2 = 0.f, s3 = 0.f;
#pragma unroll
        for (int it = 0; it < 4; it++) {
            int e = l + it * 16;
            float w0 = vld[it] ? __expf(ev[it][0] - m0) : 0.f;
            float w1 = vld[it] ? __expf(ev[it][1] - m1) : 0.f;
            float w2 = vld[it] ? __expf(ev[it][2] - m2) : 0.f;
            float w3 = vld[it] ? __expf(ev[it][3] - m3) : 0.f;
            s0 += w0; s1 += w1; s2 += w2; s3 += w3;
            ((float4*)(lw + e * 4))[0] = make_float4(w0, w1, w2, w3);  // unconditional
        }
#pragma unroll
        for (int off = 8; off > 0; off >>= 1) {
            s0 += __shfl_xor(s0, off, 16); s1 += __shfl_xor(s1, off, 16);
            s2 += __shfl_xor(s2, off, 16); s3 += __shfl_xor(s3, off, 16);
        }
        float smh = hsel == 0 ? s0 : hsel == 1 ? s1 : hsel == 2 ? s2 : s3;
        inv = 1.f / (smh + 1e-16f);
    }

    __syncthreads();   // block-uniform handoff: staging -> gather

    float4 acc = {0.f, 0.f, 0.f, 0.f};
    if (fast) {
        // ---- gather: lane l fetches float4 chunk l of each src row, 8 deep ----
        int e = 0;
        for (; e + 8 <= len; e += 8) {
            int i0 = cp[e + 0], i1 = cp[e + 1], i2 = cp[e + 2], i3 = cp[e + 3];
            int i4 = cp[e + 4], i5 = cp[e + 5], i6 = cp[e + 6], i7 = cp[e + 7];
            float w0 = lw[(e + 0) * 4 + hsel], w1 = lw[(e + 1) * 4 + hsel];
            float w2 = lw[(e + 2) * 4 + hsel], w3 = lw[(e + 3) * 4 + hsel];
            float w4 = lw[(e + 4) * 4 + hsel], w5 = lw[(e + 5) * 4 + hsel];
            float w6 = lw[(e + 6) * 4 + hsel], w7 = lw[(e + 7) * 4 + hsel];
            float4 h0 = Hp[(size_t)i0 * 16];
            float4 h1 = Hp[(size_t)i1 * 16];
            float4 h2 = Hp[(size_t)i2 * 16];
            float4 h3 = Hp[(size_t)i3 * 16];
            float4 h4 = Hp[(size_t)i4 * 16];
            float4 h5 = Hp[(size_t)i5 * 16];
            float4 h6 = Hp[(size_t)i6 * 16];
            float4 h7 = Hp[(size_t)i7 * 16];
            acc.x += w0 * h0.x + w1 * h1.x + w2 * h2.x + w3 * h3.x
                   + w4 * h4.x + w5 * h5.x + w6 * h6.x + w7 * h7.x;
            acc.y += w0 * h0.y + w1 * h1.y + w2 * h2.y + w3 * h3.y
                   + w4 * h4.y + w5 * h5.y + w6 * h6.y + w7 * h7.y;
            acc.z += w0 * h0.z + w1 * h1.z + w2 * h2.z + w3 * h3.z
                   + w4 * h4.z + w5 * h5.z + w6 * h6.z + w7 * h7.z;
            acc.w += w0 * h0.w + w1 * h1.w + w2 * h2.w + w3 * h3.w
                   + w4 * h4.w + w5 * h5.w + w6 * h6.w + w7 * h7.w;
        }
        for (; e + 4 <= len; e += 4) {
            int i0 = cp[e + 0], i1 = cp[e + 1], i2 = cp[e + 2], i3 = cp[e + 3];
            float w0 = lw[(e + 0) * 4 + hsel], w1 = lw[(e + 1) * 4 + hsel];
            float w2 = lw[(e + 2) * 4 + hsel], w3 = lw[(e + 3) * 4 + hsel];
            float4 h0 = Hp[(size_t)i0 * 16];
            float4 h1 = Hp[(size_t)i1 * 16];
            float4 h2 = Hp[(size_t)i2 * 16];
            float4 h3 = Hp[(size_t)i3 * 16];
            acc.x += w0 * h0.x + w1 * h1.x + w2 * h2.x + w3 * h3.x;
            acc.y += w0 * h0.y + w1 * h1.y + w2 * h2.y + w3 * h3.y;
            acc.z += w0 * h0.z + w1 * h1.z + w2 * h2.z + w3 * h3.z;
            acc.w += w0 * h0.w + w1 * h1.w + w2 * h2.w + w3 * h3.w;
        }
        for (; e < len; e++) {
            int i0 = cp[e];
            float w0 = lw[e * 4 + hsel];
            float4 h0 = Hp[(size_t)i0 * 16];
            acc.x += w0 * h0.x; acc.y += w0 * h0.y;
            acc.z += w0 * h0.z; acc.w += w0 * h0.w;
        }
    } else {
        // vanishingly-rare fallback (deg > 64): 3-phase recompute, no LDS
        float m0 = -1e30f, m1 = -1e30f, m2 = -1e30f, m3 = -1e30f;
        for (int e = l; e < len; e += 16) {
            int s = cp[e];
            float4 a = ((const float4*)als)[s];
            m0 = fmaxf(m0, lrelu(a.x + ad4.x)); m1 = fmaxf(m1, lrelu(a.y + ad4.y));
            m2 = fmaxf(m2, lrelu(a.z + ad4.z)); m3 = fmaxf(m3, lrelu(a.w + ad4.w));
        }
#pragma unroll
        for (int off = 8; off > 0; off >>= 1) {
            m0 = fmaxf(m0, __shfl_xor(m0, off, 16));
            m1 = fmaxf(m1, __shfl_xor(m1, off, 16));
            m2 = fmaxf(m2, __shfl_xor(m2, off, 16));
            m3 = fmaxf(m3, __shfl_xor(m3, off, 16));
        }
        float s0 = 0.f, s1 = 0.f, s2 = 0.f, s3 = 0.f;
        for (int e = l; e < len; e += 16) {
            int s = cp[e];
            float4 a = ((const float4*)als)[s];
            s0 += __expf(lrelu(a.x + ad4.x) - m0); s1 += __expf(lrelu(a.y + ad4.y) - m1);
            s2 += __expf(lrelu(a.z + ad4.z) - m2); s3 += __expf(lrelu(a.w + ad4.w) - m3);
        }
#pragma unroll
        for (int off = 8; off > 0; off >>= 1) {
            s0 += __shfl_xor(s0, off, 16); s1 += __shfl_xor(s1, off, 16);
            s2 += __shfl_xor(s2, off, 16); s3 += __shfl_xor(s3, off, 16);
        }
        float mh = hsel == 0 ? m0 : hsel == 1 ? m1 : hsel == 2 ? m2 : m3;
        float sh = hsel == 0 ? s0 : hsel == 1 ? s1 : hsel == 2 ? s2 : s3;
        float ih = 1.f / (sh + 1e-16f);
        float ah = hsel == 0 ? ad4.x : hsel == 1 ? ad4.y : hsel == 2 ? ad4.z : ad4.w;
        for (int e = 0; e < len; e++) {
            int s = cp[e];
            float alpha = __expf(lrelu(als[(size_t)s * 4 + hsel] + ah) - mh) * ih;
            float4 h0 = Hp[(size_t)s * 16];
            acc.x += alpha * h0.x; acc.y += alpha * h0.y;
            acc.z += alpha * h0.z; acc.w += alpha * h0.w;
        }
        inv = 1.f;
    }

    float4 b4 = ((const float4*)bias)[l];
    float4 o4;
    o4.x = fmaxf(acc.x * inv + b4.x, 0.f);
    o4.y = fmaxf(acc.y * inv + b4.y, 0.f);
    o4.z = fmaxf(acc.z * inv + b4.z, 0.f);
    o4.w = fmaxf(acc.w * inv + b4.w, 0.f);
    if (!last) {
        ((float4*)Hout)[(size_t)n * 16 + l] = o4;
    } else {
        // fused sum-pool + head linear: one atomic per node
        float4 w4 = ((const float4*)hw)[l];
        float t = o4.x * w4.x + o4.y * w4.y + o4.z * w4.z + o4.w * w4.w;
#pragma unroll
        for (int off = 8; off > 0; off >>= 1) t += __shfl_xor(t, off, 16);
        if (l == 0) atomicAdd(&out[batch[n]], t);
    }
}

// ---------------- output init ------------------------------------------------
__global__ void k_out_init(const float* __restrict__ head_b, float* __restrict__ out) {
    int g = blockIdx.x * blockDim.x + threadIdx.x;
    if (g < GG) out[g] = head_b[0];
}

// ---------------- launch -----------------------------------------------------
extern "C" void kernel_launch(void* const* d_in, const int* in_sizes, int n_in,
                              void* d_out, int out_size, void* d_ws, size_t ws_size,
                              hipStream_t stream) {
    const float* x     = (const float*)d_in[0];
    const int*   ei    = (const int*)d_in[1];
    const int*   batch = (const int*)d_in[2];
    const float* Wm[3] = {(const float*)d_in[3], (const float*)d_in[7],  (const float*)d_in[11]};
    const float* As[3] = {(const float*)d_in[4], (const float*)d_in[8],  (const float*)d_in[12]};
    const float* Ad[3] = {(const float*)d_in[5], (const float*)d_in[9],  (const float*)d_in[13]};
    const float* Bb[3] = {(const float*)d_in[6], (const float*)d_in[10], (const float*)d_in[14]};
    const float* hw = (const float*)d_in[15];
    const float* hb = (const float*)d_in[16];
    float* out = (float*)d_out;

    uint8_t* w = (uint8_t*)d_ws;
    auto alloc = [&](size_t bytes) -> void* {
        void* p = (void*)w;
        w += (bytes + 255) & ~(size_t)255;
        return p;
    };
    float* H     = (float*)alloc((size_t)NN * 64 * 4);     // fp32 gather rows
    float* Bf    = (float*)alloc((size_t)NN * 64 * 4);     // aggregated output
    float* als   = (float*)alloc((size_t)NN * 4 * 4);
    float* ald   = (float*)alloc((size_t)NN * 4 * 4);
    int*   deg   = (int*)alloc((size_t)NN * 4);
    int*   offs  = (int*)alloc((size_t)NN * 4);
    int*   rank  = (int*)alloc((size_t)EN * 4);
    int*   col   = (int*)alloc((size_t)EN * 4);
    int*   bsums = (int*)alloc((size_t)((NB_SCAN + 63) & ~63) * 4);

    hipMemsetAsync(deg, 0, (size_t)NN * 4, stream);

    int eb = (EN + 255) / 256;
    k_count  <<<eb, 256, 0, stream>>>(ei, deg, rank);
    k_scan1  <<<NB_SCAN, 256, 0, stream>>>(deg, offs, bsums);
    k_scan2  <<<1, 512, 0, stream>>>(bsums);
    k_scan3  <<<NB_SCAN, 256, 0, stream>>>(offs, bsums);
    k_scatter<<<eb, 256, 0, stream>>>(ei, offs, rank, col);
    k_out_init<<<(GG + 255) / 256, 256, 0, stream>>>(hb, out);

    const float* cur_in = x;
    for (int L = 0; L < 3; L++) {
        if (L == 0)
            k_gemm<128><<<NN / 16, 256, 0, stream>>>(
                cur_in, Wm[L], As[L], Ad[L], H, als, ald);
        else
            k_gemm<64><<<NN / 16, 256, 0, stream>>>(
                cur_in, Wm[L], As[L], Ad[L], H, als, ald);
        k_agg <<<NN / 16, 256, 0, stream>>>(
            H, als, ald, offs, deg, col, Bb[L], Bf, batch, hw, out, (L == 2) ? 1 : 0);
        cur_in = Bf;
    }
}